// Round 1
// baseline (547.785 us; speedup 1.0000x reference)
//
#include <hip/hip_runtime.h>
#include <hip/hip_bf16.h>
#include <stdint.h>

// Problem constants
#define B_ 4
#define S_ 2048
#define D_ 256
#define H_ 8

using f32x4  = __attribute__((ext_vector_type(4))) float;
using bf16x8 = __attribute__((ext_vector_type(8))) __bf16;

static __device__ __forceinline__ unsigned short f2bf(float x) {
    union { float f; unsigned u; } v; v.f = x;
    unsigned r = (v.u + 0x7FFFu + ((v.u >> 16) & 1u)) >> 16;
    return (unsigned short)r;
}

static __device__ __forceinline__ f32x4 mfma_bf16(bf16x8 a, bf16x8 b, f32x4 c) {
    return __builtin_amdgcn_mfma_f32_16x16x32_bf16(a, b, c, 0, 0, 0);
}

// ---------------------------------------------------------------------------
// Kernel 0: transpose + bf16-convert weights.
// WqkvT[which][h][n][d] = W_{which}[h][d][n]   (3*8*256*256 bf16)
// WmhT[n][k]           = W_mh[k][n]            (256*2048 bf16)
// ---------------------------------------------------------------------------
__global__ __launch_bounds__(256) void wtrans_kernel(
        const float* __restrict__ Wq, const float* __restrict__ Wk,
        const float* __restrict__ Wv, const float* __restrict__ Wmh,
        unsigned short* __restrict__ WqkvT, unsigned short* __restrict__ WmhT) {
    int idx = blockIdx.x * 256 + threadIdx.x;
    const int NQKV = 3 * H_ * 256 * 256;
    if (idx < NQKV) {
        int d = idx & 255, n = (idx >> 8) & 255, h = (idx >> 16) & 7, which = idx >> 19;
        const float* W = (which == 0) ? Wq : ((which == 1) ? Wk : Wv);
        WqkvT[idx] = f2bf(W[(h * 256 + d) * 256 + n]);
    } else {
        int j = idx - NQKV;            // j = n*2048 + k
        int k = j & 2047, n = j >> 11;
        WmhT[j] = f2bf(Wmh[k * 256 + n]);
    }
}

// ---------------------------------------------------------------------------
// Kernel 1: projections. Per block: one 64x64 tile of (X @ W_h) for one of
// Q/K/V and one head. X is fp32 [B*S, 256]; W comes pre-transposed bf16.
// Outputs: Qh,Kh as [b,h,s,k] bf16; V as VhT[b,h,v,s] bf16 (transposed for PV).
// blockIdx.x = nt(4) | h(8) | which(3)  (X-tile reuse across consecutive blocks)
// blockIdx.y = mt (128)
// ---------------------------------------------------------------------------
__global__ __launch_bounds__(256, 2) void proj_kernel(
        const float* __restrict__ Q, const float* __restrict__ K,
        const float* __restrict__ V, const unsigned short* __restrict__ WqkvT,
        unsigned short* __restrict__ Qh, unsigned short* __restrict__ Kh,
        unsigned short* __restrict__ VhT) {
    __shared__ __attribute__((aligned(16))) unsigned char smem[65536];
    // [0,32768):  A tile  [64 m][256 k] bf16, 512B rows, XOR-swizzled
    // [32768,..): WT tile [64 n][256 k] bf16, 512B rows, XOR-swizzled
    int tid = threadIdx.x;
    int nt = blockIdx.x & 3, h = (blockIdx.x >> 2) & 7, which = blockIdx.x >> 5;
    int mt = blockIdx.y;
    const float* X = (which == 0) ? Q : ((which == 1) ? K : V);

    { // stage A: fp32 -> bf16
        const float4* Xv = (const float4*)(X + (size_t)mt * 64 * 256);
        #pragma unroll
        for (int j = 0; j < 16; ++j) {
            int c = tid + 256 * j;              // c = row*64 + c4
            int row = c >> 6, c4 = c & 63;
            float4 x = Xv[c];
            ushort4 p;
            p.x = f2bf(x.x); p.y = f2bf(x.y); p.z = f2bf(x.z); p.w = f2bf(x.w);
            *(ushort4*)(smem + row * 512 + ((c4 * 8) ^ ((row & 7) << 4))) = p;
        }
    }
    { // stage WT (already bf16, already [n][d])
        const uint4* Wv_ = (const uint4*)(WqkvT + (size_t)((which * H_ + h) * 256 + nt * 64) * 256);
        #pragma unroll
        for (int j = 0; j < 8; ++j) {
            int c = tid + 256 * j;              // c = row*32 + slot
            int row = c >> 5, slot = c & 31;
            *(uint4*)(smem + 32768 + row * 512 + ((slot * 16) ^ ((row & 7) << 4))) = Wv_[c];
        }
    }
    __syncthreads();

    int w = tid >> 6, l = tid & 63, lr = l & 15, lg = l >> 4;
    f32x4 acc[4];
    #pragma unroll
    for (int fr = 0; fr < 4; ++fr) acc[fr] = (f32x4){0.f, 0.f, 0.f, 0.f};

    #pragma unroll
    for (int ks = 0; ks < 8; ++ks) {
        int arow = 16 * w + lr;
        bf16x8 a = *(const bf16x8*)(smem + arow * 512 + ((64 * ks + 16 * lg) ^ ((arow & 7) << 4)));
        #pragma unroll
        for (int fr = 0; fr < 4; ++fr) {
            int brow = 16 * fr + lr;
            bf16x8 b = *(const bf16x8*)(smem + 32768 + brow * 512 + ((64 * ks + 16 * lg) ^ ((brow & 7) << 4)));
            acc[fr] = mfma_bf16(a, b, acc[fr]);
        }
    }

    int m0 = mt * 64 + 16 * w + 4 * lg;   // first of 4 consecutive m rows
    int b = m0 >> 11, s0 = m0 & 2047;
    if (which < 2) {
        unsigned short* out = (which == 0) ? Qh : Kh;
        #pragma unroll
        for (int fr = 0; fr < 4; ++fr) {
            int n = nt * 64 + 16 * fr + lr;
            #pragma unroll
            for (int i = 0; i < 4; ++i)
                out[(size_t)((b * H_ + h) * S_ + s0 + i) * D_ + n] = f2bf(acc[fr][i]);
        }
    } else {
        #pragma unroll
        for (int fr = 0; fr < 4; ++fr) {
            int n = nt * 64 + 16 * fr + lr;
            ushort4 p;
            p.x = f2bf(acc[fr][0]); p.y = f2bf(acc[fr][1]);
            p.z = f2bf(acc[fr][2]); p.w = f2bf(acc[fr][3]);
            *(ushort4*)(VhT + (size_t)((b * H_ + h) * D_ + n) * S_ + s0) = p;
        }
    }
}

// ---------------------------------------------------------------------------
// Kernel 2: flash attention with multiplicative mask.
// Block = (qt, h, b), 256 threads = 4 waves, each wave owns 16 q rows.
// K tile [64 t][256 dk] and VT tile [256 v][64 t] staged in swizzled LDS.
// Scores/softmax in registers (16-lane-group shfl reduces); P via per-wave LDS.
// heads written into the Qh buffer (each block reads only its own q rows).
// ---------------------------------------------------------------------------
__global__ __launch_bounds__(256, 2) void attn_kernel(
        const unsigned short* Qh, const unsigned short* __restrict__ Kh,
        const unsigned short* __restrict__ VhT, const float* __restrict__ M,
        unsigned short* heads) {
    __shared__ __attribute__((aligned(16))) unsigned char smem[73728];
    // [0,32768):      K tile  [64][512B] swz
    // [32768,65536):  VT tile [256][128B] swz
    // [65536,73728):  P tiles, per-wave 2KB: [16 q][128B] swz
    int tid = threadIdx.x;
    int qt = blockIdx.x, h = blockIdx.y, b = blockIdx.z;
    int bh = b * H_ + h;
    int w = tid >> 6, l = tid & 63, lr = l & 15, lg = l >> 4;

    const unsigned short* KhP = Kh + (size_t)bh * S_ * D_;
    const unsigned short* VTP = VhT + (size_t)bh * D_ * S_;
    const float* MP = M + (size_t)b * S_ * S_;

    // hoist Q fragments (A-operand: lane holds Qh[q = l&15 of wave tile][8 contig dk])
    bf16x8 qf[8];
    {
        int qrow = qt * 64 + 16 * w + lr;
        const unsigned short* QhP = Qh + (size_t)(bh * S_ + qrow) * D_;
        #pragma unroll
        for (int ks = 0; ks < 8; ++ks)
            qf[ks] = *(const bf16x8*)(QhP + 32 * ks + 8 * lg);
    }

    f32x4 o[16];
    #pragma unroll
    for (int vf = 0; vf < 16; ++vf) o[vf] = (f32x4){0.f, 0.f, 0.f, 0.f};
    float mrun[4], lrun[4];
    #pragma unroll
    for (int i = 0; i < 4; ++i) { mrun[i] = -1e30f; lrun[i] = 0.f; }

    int q0 = qt * 64 + 16 * w + 4 * lg;      // first of this lane's 4 q rows
    unsigned char* plds = smem + 65536 + w * 2048;

    for (int tt = 0; tt < 32; ++tt) {
        __syncthreads();
        { // stage K tile
            const uint4* src = (const uint4*)(KhP + (size_t)tt * 64 * 256);
            #pragma unroll
            for (int j = 0; j < 8; ++j) {
                int c = tid + 256 * j;          // c = row*32 + slot
                int row = c >> 5, slot = c & 31;
                *(uint4*)(smem + row * 512 + ((slot * 16) ^ ((row & 7) << 4))) = src[c];
            }
        }
        { // stage VT tile
            #pragma unroll
            for (int j = 0; j < 8; ++j) {
                int c = tid + 256 * j;          // c = v*8 + slot
                int v = c >> 3, slot = c & 7;
                uint4 x = *(const uint4*)(VTP + (size_t)v * S_ + tt * 64 + slot * 8);
                *(uint4*)(smem + 32768 + v * 128 + ((slot * 16) ^ ((v & 7) << 4))) = x;
            }
        }
        __syncthreads();

        // QK^T: per wave 16q x 64t
        f32x4 sacc[4];
        #pragma unroll
        for (int fr = 0; fr < 4; ++fr) sacc[fr] = (f32x4){0.f, 0.f, 0.f, 0.f};
        #pragma unroll
        for (int ks = 0; ks < 8; ++ks) {
            #pragma unroll
            for (int fr = 0; fr < 4; ++fr) {
                int brow = 16 * fr + lr;
                bf16x8 bb = *(const bf16x8*)(smem + brow * 512 + ((64 * ks + 16 * lg) ^ ((brow & 7) << 4)));
                sacc[fr] = mfma_bf16(qf[ks], bb, sacc[fr]);
            }
        }

        // scale * multiplicative mask (before softmax), fp32
        float p[4][4];
        #pragma unroll
        for (int fr = 0; fr < 4; ++fr) {
            int tg = tt * 64 + 16 * fr + lr;
            #pragma unroll
            for (int i = 0; i < 4; ++i) {
                float mv = MP[(size_t)(q0 + i) * S_ + tg];
                p[fr][i] = sacc[fr][i] * 0.0625f * mv;
            }
        }

        // online softmax: row r=4*lg+i lives in the 16 lanes of this lane-group
        #pragma unroll
        for (int i = 0; i < 4; ++i) {
            float mx = fmaxf(fmaxf(p[0][i], p[1][i]), fmaxf(p[2][i], p[3][i]));
            #pragma unroll
            for (int dd = 1; dd < 16; dd <<= 1) mx = fmaxf(mx, __shfl_xor(mx, dd, 64));
            float mn = fmaxf(mrun[i], mx);
            float f = __expf(mrun[i] - mn);
            float rs = 0.f;
            #pragma unroll
            for (int fr = 0; fr < 4; ++fr) { p[fr][i] = __expf(p[fr][i] - mn); rs += p[fr][i]; }
            #pragma unroll
            for (int dd = 1; dd < 16; dd <<= 1) rs += __shfl_xor(rs, dd, 64);
            lrun[i] = lrun[i] * f + rs;
            mrun[i] = mn;
            #pragma unroll
            for (int vf = 0; vf < 16; ++vf) o[vf][i] *= f;
        }

        // P -> bf16 -> per-wave LDS tile [16 q][64 t] swz
        #pragma unroll
        for (int i = 0; i < 4; ++i) {
            int row = 4 * lg + i;
            #pragma unroll
            for (int fr = 0; fr < 4; ++fr)
                *(unsigned short*)(plds + row * 128 + (((16 * fr + lr) * 2) ^ ((row & 7) << 4))) =
                    f2bf(p[fr][i]);
        }

        // PV: O[16q x 256v] += P[16q x 64t] * V[64t x 256v]
        #pragma unroll
        for (int ks2 = 0; ks2 < 2; ++ks2) {
            int prow = lr;
            bf16x8 pa = *(const bf16x8*)(plds + prow * 128 + ((64 * ks2 + 16 * lg) ^ ((prow & 7) << 4)));
            #pragma unroll
            for (int vf = 0; vf < 16; ++vf) {
                int vrow = 16 * vf + lr;
                bf16x8 bv = *(const bf16x8*)(smem + 32768 + vrow * 128 + ((64 * ks2 + 16 * lg) ^ ((vrow & 7) << 4)));
                o[vf] = mfma_bf16(pa, bv, o[vf]);
            }
        }
    }

    // epilogue: normalize and write heads (bf16) into the Qh buffer
    #pragma unroll
    for (int i = 0; i < 4; ++i) {
        float inv = 1.f / lrun[i];
        unsigned short* hp = heads + (size_t)(bh * S_ + q0 + i) * D_;
        #pragma unroll
        for (int vf = 0; vf < 16; ++vf)
            hp[16 * vf + lr] = f2bf(o[vf][i] * inv);
    }
}

// ---------------------------------------------------------------------------
// Kernel 3: output projection. out[m, n] = sum_{h,v} heads[b,h,s,v] * Wmh[hv, n]
// K-loop over h (each h-chunk is 256 contiguous v). fp32 output.
// ---------------------------------------------------------------------------
__global__ __launch_bounds__(256, 2) void out_kernel(
        const unsigned short* __restrict__ heads,
        const unsigned short* __restrict__ WmhT, float* __restrict__ out) {
    __shared__ __attribute__((aligned(16))) unsigned char smem[65536];
    int tid = threadIdx.x;
    int nt = blockIdx.x, mt = blockIdx.y;
    int w = tid >> 6, l = tid & 63, lr = l & 15, lg = l >> 4;
    int m0 = mt * 64;
    int b = m0 >> 11, s00 = m0 & 2047;

    f32x4 acc[4];
    #pragma unroll
    for (int fr = 0; fr < 4; ++fr) acc[fr] = (f32x4){0.f, 0.f, 0.f, 0.f};

    for (int h = 0; h < H_; ++h) {
        __syncthreads();
        { // stage A tile: heads[b,h, s00..s00+64, 0..256]
            const uint4* src = (const uint4*)(heads + (size_t)((b * H_ + h) * S_ + s00) * D_);
            #pragma unroll
            for (int j = 0; j < 8; ++j) {
                int c = tid + 256 * j;
                int row = c >> 5, slot = c & 31;
                *(uint4*)(smem + row * 512 + ((slot * 16) ^ ((row & 7) << 4))) = src[c];
            }
        }
        { // stage WT tile: WmhT[nt*64+row][h*256 + slot*8]
            #pragma unroll
            for (int j = 0; j < 8; ++j) {
                int c = tid + 256 * j;
                int row = c >> 5, slot = c & 31;
                uint4 x = *(const uint4*)(WmhT + (size_t)(nt * 64 + row) * 2048 + h * 256 + slot * 8);
                *(uint4*)(smem + 32768 + row * 512 + ((slot * 16) ^ ((row & 7) << 4))) = x;
            }
        }
        __syncthreads();
        #pragma unroll
        for (int ks = 0; ks < 8; ++ks) {
            int arow = 16 * w + lr;
            bf16x8 a = *(const bf16x8*)(smem + arow * 512 + ((64 * ks + 16 * lg) ^ ((arow & 7) << 4)));
            #pragma unroll
            for (int fr = 0; fr < 4; ++fr) {
                int brow = 16 * fr + lr;
                bf16x8 bb = *(const bf16x8*)(smem + 32768 + brow * 512 + ((64 * ks + 16 * lg) ^ ((brow & 7) << 4)));
                acc[fr] = mfma_bf16(a, bb, acc[fr]);
            }
        }
    }

    int mrow = mt * 64 + 16 * w + 4 * lg;
    #pragma unroll
    for (int fr = 0; fr < 4; ++fr) {
        int n = nt * 64 + 16 * fr + lr;
        #pragma unroll
        for (int i = 0; i < 4; ++i)
            out[(size_t)(mrow + i) * D_ + n] = acc[fr][i];
    }
}

// ---------------------------------------------------------------------------
extern "C" void kernel_launch(void* const* d_in, const int* in_sizes, int n_in,
                              void* d_out, int out_size, void* d_ws, size_t ws_size,
                              hipStream_t stream) {
    const float* Q   = (const float*)d_in[0];
    const float* K   = (const float*)d_in[1];
    const float* V   = (const float*)d_in[2];
    const float* M   = (const float*)d_in[3];
    const float* Wq  = (const float*)d_in[4];
    const float* Wk  = (const float*)d_in[5];
    const float* Wv  = (const float*)d_in[6];
    const float* Wmh = (const float*)d_in[7];
    float* out = (float*)d_out;

    char* ws = (char*)d_ws;
    // ws layout (bytes):
    //   [0,   32M): Qh  bf16 [B,H,S,D]   -- later overwritten with heads
    //   [32M, 64M): Kh  bf16 [B,H,S,D]
    //   [64M, 96M): VhT bf16 [B,H,D,S]
    //   [96M, 99M): WqkvT bf16 [3,H,256,256]
    //   [99M,100M): WmhT  bf16 [256,2048]
    unsigned short* Qh    = (unsigned short*)(ws);
    unsigned short* Kh    = (unsigned short*)(ws + 33554432);
    unsigned short* VhT   = (unsigned short*)(ws + 67108864);
    unsigned short* WqkvT = (unsigned short*)(ws + 100663296);
    unsigned short* WmhT  = (unsigned short*)(ws + 103809024);

    wtrans_kernel<<<dim3(8192), dim3(256), 0, stream>>>(Wq, Wk, Wv, Wmh, WqkvT, WmhT);
    proj_kernel<<<dim3(96, 128), dim3(256), 0, stream>>>(Q, K, V, WqkvT, Qh, Kh, VhT);
    attn_kernel<<<dim3(32, 8, 4), dim3(256), 0, stream>>>(Qh, Kh, VhT, M, /*heads=*/Qh);
    out_kernel<<<dim3(4, 128), dim3(256), 0, stream>>>(/*heads=*/Qh, WmhT, out);
}